// Round 1
// baseline (2318.899 us; speedup 1.0000x reference)
//
#include <hip/hip_runtime.h>
#include <math.h>

// Problem constants
#define NCELLS 131072
#define IND 64
#define HD 128
#define OUTD 64
#define CATD 192          // IND + HD
#define NF 8
#define FS 16384          // NCELLS / NF
#define DC 4096           // FS / 4
#define TB 16             // cells per block
#define NBLK (NCELLS/TB)  // 8192

// Shared-memory layout (float indices). Strides padded co-prime with 32 banks.
// scratch region is reused: h1buf (GEMM1->GEMM2) then rz (GRU gates phase).
#define OFF_C    0        // cbuf  [16][193]  = 3088
#define OFF_OUT  3088     // out   [16][65]   = 1040
#define OFF_TL   4128     // t     [16]
#define OFF_EL   4144     // e^t   [16]
#define OFF_HNEW 4160     // hnew  [16][129]  = 2064
#define OFF_SCR  6224     // h1buf/rz [16][257] = 4112
#define OFF_IN   10336    // i_n   [16][129]  = 2064
#define OFF_HNB  12400    // h_n   [16][129]  = 2064
#define SMEM_F   14464    // 57,856 bytes

__global__ __launch_bounds__(256) void fused_cell_kernel(
    const float* __restrict__ x,   const float* __restrict__ hiddens,
    const float* __restrict__ W1a, const float* __restrict__ b1a,
    const float* __restrict__ W2a, const float* __restrict__ b2a,
    const float* __restrict__ W1g, const float* __restrict__ b1g,
    const float* __restrict__ W2g, const float* __restrict__ b2g,
    const float* __restrict__ Wih, const float* __restrict__ Whh,
    const float* __restrict__ bih, const float* __restrict__ bhh,
    float* __restrict__ newh,      // d_out + 65 (pre-sync h written here)
    float* __restrict__ fsum, float* __restrict__ wsum,
    float* __restrict__ sumexp, float* __restrict__ tsum)
{
    __shared__ float sm[SMEM_F];
    const int tid = threadIdx.x;
    const int cell0 = blockIdx.x * TB;

    // ---- stage c = [x | hidden] tile ----
    for (int idx = tid; idx < TB*CATD; idx += 256) {
        const int c = idx / CATD, k = idx - c*CATD;
        const float v = (k < IND) ? x[k]
                                  : hiddens[(size_t)(cell0+c)*HD + (k-IND)];
        sm[OFF_C + c*193 + k] = v;
    }
    __syncthreads();

    // ---- GEMM1: h1[0:128]=relu(c@W1a.T+b1a), h1[128:256]=relu(c@W1g.T+b1g) ----
    {
        const int c  = tid & 15;
        const int cg = tid >> 4;              // 0..15 col-groups of 16
        const float* Wb = (cg < 8) ? W1a : W1g;
        const float* bb = (cg < 8) ? b1a : b1g;
        const int colloc = (cg & 7) * 16;     // row within W1a/W1g
        const int colbase = cg * 16;          // position in fused h1
        float acc[16];
        #pragma unroll
        for (int j = 0; j < 16; ++j) acc[j] = bb[colloc+j];
        for (int k = 0; k < CATD; k += 8) {
            float cv[8];
            #pragma unroll
            for (int q = 0; q < 8; ++q) cv[q] = sm[OFF_C + c*193 + k + q];
            #pragma unroll
            for (int j = 0; j < 16; ++j) {
                const float* wr = Wb + (size_t)(colloc+j)*CATD + k;
                const float4 w0 = *(const float4*)wr;
                const float4 w1 = *(const float4*)(wr+4);
                acc[j] += cv[0]*w0.x + cv[1]*w0.y + cv[2]*w0.z + cv[3]*w0.w
                        + cv[4]*w1.x + cv[5]*w1.y + cv[6]*w1.z + cv[7]*w1.w;
            }
        }
        #pragma unroll
        for (int j = 0; j < 16; ++j)
            sm[OFF_SCR + c*257 + colbase + j] = fmaxf(acc[j], 0.0f);
    }
    __syncthreads();

    // ---- GEMM2: out = relu_a @ W2a.T - relu_g @ W2g.T + (b2a-b2g) ----
    {
        const int c  = tid & 15;
        const int cg = tid >> 4;              // 0..15, 4 cols each
        const int colbase = cg * 4;
        float acc[4];
        #pragma unroll
        for (int j = 0; j < 4; ++j) acc[j] = b2a[colbase+j] - b2g[colbase+j];
        for (int k = 0; k < HD; k += 8) {
            float ha[8], hg[8];
            #pragma unroll
            for (int q = 0; q < 8; ++q) {
                ha[q] = sm[OFF_SCR + c*257 + k + q];
                hg[q] = sm[OFF_SCR + c*257 + 128 + k + q];
            }
            #pragma unroll
            for (int j = 0; j < 4; ++j) {
                const int col = colbase + j;
                const float* wa = W2a + (size_t)col*HD + k;
                const float* wg = W2g + (size_t)col*HD + k;
                const float4 a0 = *(const float4*)wa;
                const float4 a1 = *(const float4*)(wa+4);
                const float4 g0 = *(const float4*)wg;
                const float4 g1 = *(const float4*)(wg+4);
                acc[j] += ha[0]*a0.x + ha[1]*a0.y + ha[2]*a0.z + ha[3]*a0.w
                        + ha[4]*a1.x + ha[5]*a1.y + ha[6]*a1.z + ha[7]*a1.w
                        - hg[0]*g0.x - hg[1]*g0.y - hg[2]*g0.z - hg[3]*g0.w
                        - hg[4]*g1.x - hg[5]*g1.y - hg[6]*g1.z - hg[7]*g1.w;
            }
        }
        #pragma unroll
        for (int j = 0; j < 4; ++j) sm[OFF_OUT + c*65 + colbase + j] = acc[j];
    }
    __syncthreads();

    // ---- t = mean(out^2) per cell ----
    if (tid < TB) {
        float s = 0.f;
        #pragma unroll 8
        for (int j = 0; j < OUTD; ++j) {
            const float v = sm[OFF_OUT + tid*65 + j];
            s += v*v;
        }
        const float t = s * (1.0f/OUTD);
        sm[OFF_TL + tid] = t;
        sm[OFF_EL + tid] = expf(t);
    }
    __syncthreads();

    // ---- GRU gate GEMMs: gi = [out|t]@Wih.T+bih, gh = h@Whh.T+bhh ----
    // scratch region now reused for r/z (h1buf dead)
    {
        const int c  = tid & 15;
        const int jg = tid >> 4;              // 0..15, 24 j's each (384 total)
        const float tv = sm[OFF_TL + c];
        for (int jj = 0; jj < 24; ++jj) {
            const int j = jg*24 + jj;
            const float* wi = Wih + (size_t)j*(OUTD+1);
            float ai = bih[j];
            #pragma unroll 8
            for (int k = 0; k < OUTD; ++k) ai += sm[OFF_OUT + c*65 + k] * wi[k];
            ai += tv * wi[OUTD];
            const float* wh = Whh + (size_t)j*HD;
            float ah = bhh[j];
            for (int k = 0; k < HD; k += 8) {
                const float4 w0 = *(const float4*)(wh+k);
                const float4 w1 = *(const float4*)(wh+k+4);
                const int hb = OFF_C + c*193 + IND + k;
                ah += sm[hb  ]*w0.x + sm[hb+1]*w0.y + sm[hb+2]*w0.z + sm[hb+3]*w0.w
                    + sm[hb+4]*w1.x + sm[hb+5]*w1.y + sm[hb+6]*w1.z + sm[hb+7]*w1.w;
            }
            if (j < 2*HD) {
                sm[OFF_SCR + c*257 + j] = 1.0f/(1.0f + expf(-(ai+ah)));  // r,z
            } else {
                sm[OFF_IN  + c*129 + (j-2*HD)] = ai;   // i_n
                sm[OFF_HNB + c*129 + (j-2*HD)] = ah;   // h_n
            }
        }
    }
    __syncthreads();

    // ---- GRU elementwise -> h_pre (written to d_out region) ----
    for (int idx = tid; idx < TB*HD; idx += 256) {
        const int c = idx >> 7, j = idx & 127;
        const float r = sm[OFF_SCR + c*257 + j];
        const float z = sm[OFF_SCR + c*257 + HD + j];
        const float n = tanhf(sm[OFF_IN + c*129 + j] + r * sm[OFF_HNB + c*129 + j]);
        const float hv = (1.0f - z)*n + z*sm[OFF_C + c*193 + IND + j];
        sm[OFF_HNEW + c*129 + j] = hv;
        newh[(size_t)(cell0+c)*HD + j] = hv;
    }
    __syncthreads();

    // ---- block reductions + device atomics ----
    if (tid < HD) {   // faction partial sums (whole block is one faction: 16 | 16384)
        float s = 0.f;
        #pragma unroll 4
        for (int c = 0; c < TB; ++c) s += sm[OFF_HNEW + c*129 + tid];
        unsafeAtomicAdd(&fsum[(blockIdx.x >> 10)*HD + tid], s);
    }
    if (tid < OUTD) { // softmax-weighted out accumulation (exp(t), no max shift: t in [0,~4])
        float wacc = 0.f;
        #pragma unroll 4
        for (int c = 0; c < TB; ++c) wacc += sm[OFF_EL + c] * sm[OFF_OUT + c*65 + tid];
        unsafeAtomicAdd(&wsum[tid], wacc);
    }
    if (tid == 0) {
        float se = 0.f, ts = 0.f;
        #pragma unroll 4
        for (int c = 0; c < TB; ++c) { se += sm[OFF_EL + c]; ts += sm[OFF_TL + c]; }
        unsafeAtomicAdd(sumexp, se);
        unsafeAtomicAdd(tsum, ts);
    }
}

// Faction sync applied in place on new_h. Post-sync faction mean == pre-sync mean
// (0.85*h+0.15*fm averages back to fm), so ops==fm and go==grand mean of h_pre.
__global__ __launch_bounds__(256) void faction_kernel(
    float* __restrict__ newh, const float* __restrict__ fsum,
    const int* __restrict__ step)
{
    __shared__ float fmrow[HD], gorow[HD];
    const int cell0 = blockIdx.x * TB;
    const int f = blockIdx.x >> 10;
    if (threadIdx.x < HD) {
        const int j = threadIdx.x;
        float s = 0.f;
        #pragma unroll
        for (int ff = 0; ff < NF; ++ff) s += fsum[ff*HD + j];
        gorow[j] = s * (1.0f/NCELLS);
        fmrow[j] = fsum[f*HD + j] * (1.0f/FS);
    }
    __syncthreads();
    const bool debate = (step[0] > 5);
    for (int idx = threadIdx.x; idx < TB*HD; idx += 256) {
        const int c = idx >> 7, j = idx & 127;
        const int cell = cell0 + c;
        const size_t e = (size_t)cell*HD + j;
        float v = newh[e];
        v = 0.85f*v + 0.15f*fmrow[j];
        if (debate && (cell & (FS-1)) < DC) v = 0.85f*v + 0.15f*gorow[j];
        newh[e] = v;
    }
}

__global__ void final_kernel(const float* __restrict__ Wo, const float* __restrict__ bo,
                             const float* __restrict__ wsum, const float* __restrict__ sumexp,
                             const float* __restrict__ tsum, float* __restrict__ d_out)
{
    const int i = threadIdx.x;
    if (i < OUTD) {
        const float inv = 1.0f / sumexp[0];
        const float* wr = Wo + (size_t)i*OUTD;
        float acc = bo[i];
        for (int j = 0; j < OUTD; ++j) acc += (wsum[j]*inv) * wr[j];
        d_out[i] = acc;                     // pred
    }
    if (i == 0) d_out[OUTD] = tsum[0] * (1.0f/NCELLS);   // t.mean()
}

extern "C" void kernel_launch(void* const* d_in, const int* in_sizes, int n_in,
                              void* d_out, int out_size, void* d_ws, size_t ws_size,
                              hipStream_t stream)
{
    const float* x   = (const float*)d_in[0];
    const float* hid = (const float*)d_in[1];
    const float* W1a = (const float*)d_in[2];
    const float* b1a = (const float*)d_in[3];
    const float* W2a = (const float*)d_in[4];
    const float* b2a = (const float*)d_in[5];
    const float* W1g = (const float*)d_in[6];
    const float* b1g = (const float*)d_in[7];
    const float* W2g = (const float*)d_in[8];
    const float* b2g = (const float*)d_in[9];
    const float* Wih = (const float*)d_in[10];
    const float* Whh = (const float*)d_in[11];
    const float* bih = (const float*)d_in[12];
    const float* bhh = (const float*)d_in[13];
    const float* Wo  = (const float*)d_in[14];
    const float* bo  = (const float*)d_in[15];
    const int*  step = (const int*)d_in[16];

    float* out  = (float*)d_out;
    float* newh = out + (OUTD + 1);      // new_h region (4B aligned; scalar access)
    float* fsum   = (float*)d_ws;        // [NF][HD] = 1024
    float* wsum   = fsum + NF*HD;        // [64]
    float* sumexp = wsum + OUTD;         // [1]
    float* tsum   = sumexp + 1;          // [1]

    // accumulators are re-poisoned to 0xAA before every launch -> zero them
    hipMemsetAsync(d_ws, 0, (NF*HD + OUTD + 2)*sizeof(float), stream);

    fused_cell_kernel<<<NBLK, 256, 0, stream>>>(
        x, hid, W1a, b1a, W2a, b2a, W1g, b1g, W2g, b2g,
        Wih, Whh, bih, bhh, newh, fsum, wsum, sumexp, tsum);
    faction_kernel<<<NBLK, 256, 0, stream>>>(newh, fsum, step);
    final_kernel<<<1, 64, 0, stream>>>(Wo, bo, wsum, sumexp, tsum, out);
}

// Round 2
// 475.645 us; speedup vs baseline: 4.8753x; 4.8753x over previous
//
#include <hip/hip_runtime.h>
#include <math.h>

// Problem constants
#define NCELLS 131072
#define IND 64
#define HD 128
#define OUTD 64
#define CATD 192
#define NF 8
#define FS 16384
#define DC 4096
#define TB 32             // cells per fused block
#define NBLK (NCELLS/TB)  // 4096

typedef __bf16 bf16x8 __attribute__((ext_vector_type(8)));
typedef float f32x4 __attribute__((ext_vector_type(4)));
typedef unsigned short us8 __attribute__((ext_vector_type(8)));

#define MFMA(a,b,c) __builtin_amdgcn_mfma_f32_16x16x32_bf16(a,b,c,0,0,0)

// ---- workspace layout ----
// ushort (bf16) region:
#define WS_W1F 0          // [256][192]  fused [W1a;W1g]
#define WS_W2F 49152      // [64][256]   fused [W2a | -W2g]
#define WS_WIH 65536      // [384][96]   Wih padded K 65->96 with zeros
#define WS_WHH 102400     // [384][128]
#define WS_U_TOTAL 151552
// float region at (float*)((ushort*)ws + WS_U_TOTAL):
#define WF_B1   0         // [256] = [b1a|b1g]
#define WF_B2   256       // [64]  = b2a-b2g
#define WF_FSUM 320       // [8][128]
#define WF_WSUM 1344      // [64]
#define WF_SE   1408
#define WF_TS   1409
#define WF_TOTAL 1410

__device__ __forceinline__ unsigned short f2bf(float f) {
    unsigned u = __builtin_bit_cast(unsigned, f);
    return (unsigned short)((u + 0x7FFFu + ((u >> 16) & 1u)) >> 16);
}
__device__ __forceinline__ float bf2f(unsigned short h) {
    return __builtin_bit_cast(float, (unsigned)h << 16);
}
__device__ __forceinline__ bf16x8 ld8(const unsigned short* p) {
    return __builtin_bit_cast(bf16x8, *(const us8*)p);
}

// ---- per-launch weight conversion fp32 -> bf16 (weights re-restored each launch) ----
__global__ __launch_bounds__(256) void convert_kernel(
    const float* __restrict__ W1a, const float* __restrict__ b1a,
    const float* __restrict__ W2a, const float* __restrict__ b2a,
    const float* __restrict__ W1g, const float* __restrict__ b1g,
    const float* __restrict__ W2g, const float* __restrict__ b2g,
    const float* __restrict__ Wih, const float* __restrict__ Whh,
    unsigned short* __restrict__ wsu, float* __restrict__ wsf)
{
    int i = blockIdx.x * 256 + threadIdx.x;
    if (i < 49152) {                       // W1f
        int r = i / 192, k = i - r*192;
        float v = (r < 128) ? W1a[r*192 + k] : W1g[(r-128)*192 + k];
        wsu[WS_W1F + i] = f2bf(v); return;
    }
    int j = i - 49152;
    if (j < 16384) {                       // W2f = [W2a | -W2g]
        int r = j >> 8, k = j & 255;
        float v = (k < 128) ? W2a[r*128 + k] : -W2g[r*128 + (k-128)];
        wsu[WS_W2F + j] = f2bf(v); return;
    }
    j -= 16384;
    if (j < 36864) {                       // Wih padded to K=96
        int r = j / 96, k = j - r*96;
        float v = (k < 65) ? Wih[r*65 + k] : 0.f;
        wsu[WS_WIH + j] = f2bf(v); return;
    }
    j -= 36864;
    if (j < 49152) { wsu[WS_WHH + j] = f2bf(Whh[j]); return; }
    j -= 49152;
    if (j < 256) { wsf[WF_B1 + j] = (j < 128) ? b1a[j] : b1g[j-128]; return; }
    j -= 256;
    if (j < 64)  { wsf[WF_B2 + j] = b2a[j] - b2g[j]; return; }
}

// ---- fused per-cell pipeline, bf16 MFMA ----
// LDS strides padded: 200/264/68/104 -> row bank-step 4 (2-way aliasing, free)
__global__ __launch_bounds__(256, 3) void fused_cell_kernel(
    const float* __restrict__ x, const float* __restrict__ hiddens,
    const float* __restrict__ bih, const float* __restrict__ bhh,
    const unsigned short* __restrict__ wsu, const float* __restrict__ wsf,
    float* __restrict__ newh, float* __restrict__ fsum,
    float* __restrict__ wsum, float* __restrict__ sumexp, float* __restrict__ tsum)
{
    __shared__ __align__(16) unsigned short sc[TB*200];   // [32][200] c=[x|h] bf16
    __shared__ __align__(16) unsigned short sh1[TB*264];  // [32][264] relu(h1) bf16 (256 cols)
    __shared__ __align__(16) float sof[TB*68];            // [32][68]  out fp32
    __shared__ __align__(16) unsigned short sob[TB*104];  // [32][104] [out|t|0pad] bf16
    __shared__ float st[TB], se[TB];

    const int tid = threadIdx.x;
    const int cell0 = blockIdx.x * TB;
    const int wave = tid >> 6, lane = tid & 63;
    const int q = lane >> 4, cL = lane & 15;

    // ---- phase 0: stage c = [x|h] as bf16; zero sob pad cols ----
    for (int idx = tid; idx < TB*IND; idx += 256) {
        int c = idx >> 6, k = idx & 63;
        sc[c*200 + k] = f2bf(x[k]);
    }
    for (int idx = tid; idx < TB*(HD/4); idx += 256) {
        int c = idx >> 5, k4 = idx & 31;
        float4 v = ((const float4*)hiddens)[(size_t)(cell0+c)*(HD/4) + k4];
        unsigned p0 = (unsigned)f2bf(v.x) | ((unsigned)f2bf(v.y) << 16);
        unsigned p1 = (unsigned)f2bf(v.z) | ((unsigned)f2bf(v.w) << 16);
        *(unsigned*)&sc[c*200 + 64 + k4*4]     = p0;
        *(unsigned*)&sc[c*200 + 64 + k4*4 + 2] = p1;
    }
    for (int idx = tid; idx < TB*32; idx += 256) {   // cols 64..95 of sob
        int c = idx >> 5, k = idx & 31;
        sob[c*104 + 64 + k] = 0;
    }
    __syncthreads();

    // ---- phase 1: GEMM1  h1 = relu(c @ W1f.T + b1f), 256 fused cols ----
    for (int ct = 0; ct < 4; ++ct) {
        const int col = wave*64 + ct*16 + cL;
        const float bias = wsf[WF_B1 + col];
        f32x4 a0 = {bias,bias,bias,bias}, a1 = a0;
        const unsigned short* wp = wsu + WS_W1F + col*192 + q*8;
        #pragma unroll
        for (int k = 0; k < 6; ++k) {
            bf16x8 B  = ld8(wp + k*32);
            bf16x8 A0 = ld8(&sc[cL*200 + k*32 + q*8]);
            a0 = MFMA(A0, B, a0);
            bf16x8 A1 = ld8(&sc[(16+cL)*200 + k*32 + q*8]);
            a1 = MFMA(A1, B, a1);
        }
        #pragma unroll
        for (int r = 0; r < 4; ++r) {
            sh1[(q*4+r)*264 + col]    = f2bf(fmaxf(a0[r], 0.f));
            sh1[(16+q*4+r)*264 + col] = f2bf(fmaxf(a1[r], 0.f));
        }
    }
    __syncthreads();

    // ---- phase 2: GEMM2  out = h1 @ W2f.T + b2f  (a - g fused) ----
    {
        const int col = wave*16 + cL;     // 0..63
        const float bias = wsf[WF_B2 + col];
        f32x4 a0 = {bias,bias,bias,bias}, a1 = a0;
        const unsigned short* wp = wsu + WS_W2F + col*256 + q*8;
        #pragma unroll
        for (int k = 0; k < 8; ++k) {
            bf16x8 B  = ld8(wp + k*32);
            bf16x8 A0 = ld8(&sh1[cL*264 + k*32 + q*8]);
            a0 = MFMA(A0, B, a0);
            bf16x8 A1 = ld8(&sh1[(16+cL)*264 + k*32 + q*8]);
            a1 = MFMA(A1, B, a1);
        }
        #pragma unroll
        for (int r = 0; r < 4; ++r) {
            int r0 = q*4 + r;
            sof[r0*68 + col]        = a0[r];
            sob[r0*104 + col]       = f2bf(a0[r]);
            sof[(16+r0)*68 + col]   = a1[r];
            sob[(16+r0)*104 + col]  = f2bf(a1[r]);
        }
    }
    __syncthreads();

    // ---- phase 3: t = mean(out^2), e^t; t into gi input col 64 ----
    if (tid < TB) {
        float s = 0.f;
        #pragma unroll 8
        for (int jj = 0; jj < OUTD; ++jj) { float v = sof[tid*68 + jj]; s += v*v; }
        float t = s * (1.0f/OUTD);
        st[tid] = t; se[tid] = expf(t);
        sob[tid*104 + 64] = f2bf(t);
    }
    __syncthreads();

    // ---- phase 4: GRU gates (MFMA) + elementwise + faction partials ----
    const int f = (int)(blockIdx.x >> 9);   // 512 blocks per faction
    for (int hh = 0; hh < 2; ++hh) {
        const int hb = wave*2 + hh;         // 8 hidden-blocks of 16
        const int j = hb*16 + cL;           // hidden unit 0..127
        const float bR = bih[j]      + bhh[j];
        const float bZ = bih[HD+j]   + bhh[HD+j];
        const float bI = bih[2*HD+j];
        const float bH = bhh[2*HD+j];
        float colsum = 0.f;
        #pragma unroll
        for (int Mt = 0; Mt < 2; ++Mt) {
            f32x4 aR = {bR,bR,bR,bR}, aZ = {bZ,bZ,bZ,bZ};
            f32x4 aI = {bI,bI,bI,bI}, aH = {bH,bH,bH,bH};
            const unsigned short* wi = wsu + WS_WIH + q*8;
            #pragma unroll
            for (int k = 0; k < 3; ++k) {   // gi: A=[out|t|0], K=96
                bf16x8 A = ld8(&sob[(Mt*16+cL)*104 + k*32 + q*8]);
                aR = MFMA(A, ld8(wi + (size_t)j*96        + k*32), aR);
                aZ = MFMA(A, ld8(wi + (size_t)(HD+j)*96   + k*32), aZ);
                aI = MFMA(A, ld8(wi + (size_t)(2*HD+j)*96 + k*32), aI);
            }
            const unsigned short* wh = wsu + WS_WHH + q*8;
            #pragma unroll
            for (int k = 0; k < 4; ++k) {   // gh: A=h (c-tile offset 64), K=128
                bf16x8 A = ld8(&sc[(Mt*16+cL)*200 + 64 + k*32 + q*8]);
                aR = MFMA(A, ld8(wh + (size_t)j*128        + k*32), aR);
                aZ = MFMA(A, ld8(wh + (size_t)(HD+j)*128   + k*32), aZ);
                aH = MFMA(A, ld8(wh + (size_t)(2*HD+j)*128 + k*32), aH);
            }
            #pragma unroll
            for (int r = 0; r < 4; ++r) {
                const int row = Mt*16 + q*4 + r;
                float rr = 1.f/(1.f + expf(-aR[r]));
                float zz = 1.f/(1.f + expf(-aZ[r]));
                float nn = tanhf(aI[r] + rr*aH[r]);
                float hold = bf2f(sc[row*200 + 64 + j]);
                float hv = (1.f - zz)*nn + zz*hold;
                newh[(size_t)(cell0+row)*HD + j] = hv;
                colsum += hv;
            }
        }
        colsum += __shfl_xor(colsum, 16);
        colsum += __shfl_xor(colsum, 32);
        if (q == 0) unsafeAtomicAdd(&fsum[f*HD + j], colsum);
    }

    // ---- phase 5: softmax-weighted sums (sof/se fixed since phase-3 sync) ----
    if (tid < OUTD) {
        float wacc = 0.f;
        #pragma unroll 4
        for (int c = 0; c < TB; ++c) wacc += se[c] * sof[c*68 + tid];
        unsafeAtomicAdd(&wsum[tid], wacc);
    }
    if (tid == 0) {
        float sE = 0.f, sT = 0.f;
        #pragma unroll 4
        for (int c = 0; c < TB; ++c) { sE += se[c]; sT += st[c]; }
        unsafeAtomicAdd(sumexp, sE);
        unsafeAtomicAdd(tsum, sT);
    }
}

// ---- faction sync in place on new_h (post-sync faction mean == pre-sync mean) ----
#define TBF 16
__global__ __launch_bounds__(256) void faction_kernel(
    float* __restrict__ newh, const float* __restrict__ fsum,
    const int* __restrict__ step)
{
    __shared__ float fmrow[HD], gorow[HD];
    const int cell0 = blockIdx.x * TBF;
    const int f = blockIdx.x >> 10;          // 1024 blocks per faction
    if (threadIdx.x < HD) {
        const int j = threadIdx.x;
        float s = 0.f;
        #pragma unroll
        for (int ff = 0; ff < NF; ++ff) s += fsum[ff*HD + j];
        gorow[j] = s * (1.0f/NCELLS);
        fmrow[j] = fsum[f*HD + j] * (1.0f/FS);
    }
    __syncthreads();
    const bool debate = (step[0] > 5);
    for (int idx = threadIdx.x; idx < TBF*HD; idx += 256) {
        const int c = idx >> 7, j = idx & 127;
        const int cell = cell0 + c;
        const size_t e = (size_t)cell*HD + j;
        float v = newh[e];
        v = 0.85f*v + 0.15f*fmrow[j];
        if (debate && (cell & (FS-1)) < DC) v = 0.85f*v + 0.15f*gorow[j];
        newh[e] = v;
    }
}

__global__ void final_kernel(const float* __restrict__ Wo, const float* __restrict__ bo,
                             const float* __restrict__ wsum, const float* __restrict__ sumexp,
                             const float* __restrict__ tsum, float* __restrict__ d_out)
{
    const int i = threadIdx.x;
    if (i < OUTD) {
        const float inv = 1.0f / sumexp[0];
        const float* wr = Wo + (size_t)i*OUTD;
        float acc = bo[i];
        for (int jj = 0; jj < OUTD; ++jj) acc += (wsum[jj]*inv) * wr[jj];
        d_out[i] = acc;
    }
    if (i == 0) d_out[OUTD] = tsum[0] * (1.0f/NCELLS);
}

extern "C" void kernel_launch(void* const* d_in, const int* in_sizes, int n_in,
                              void* d_out, int out_size, void* d_ws, size_t ws_size,
                              hipStream_t stream)
{
    const float* x   = (const float*)d_in[0];
    const float* hid = (const float*)d_in[1];
    const float* W1a = (const float*)d_in[2];
    const float* b1a = (const float*)d_in[3];
    const float* W2a = (const float*)d_in[4];
    const float* b2a = (const float*)d_in[5];
    const float* W1g = (const float*)d_in[6];
    const float* b1g = (const float*)d_in[7];
    const float* W2g = (const float*)d_in[8];
    const float* b2g = (const float*)d_in[9];
    const float* Wih = (const float*)d_in[10];
    const float* Whh = (const float*)d_in[11];
    const float* bih = (const float*)d_in[12];
    const float* bhh = (const float*)d_in[13];
    const float* Wo  = (const float*)d_in[14];
    const float* bo  = (const float*)d_in[15];
    const int*  step = (const int*)d_in[16];

    float* out  = (float*)d_out;
    float* newh = out + (OUTD + 1);

    unsigned short* wsu = (unsigned short*)d_ws;
    float* wsf = (float*)(wsu + WS_U_TOTAL);
    float* fsum   = wsf + WF_FSUM;
    float* wsum   = wsf + WF_WSUM;
    float* sumexp = wsf + WF_SE;
    float* tsum   = wsf + WF_TS;

    // zero only the accumulator slice (ws is re-poisoned each launch)
    hipMemsetAsync(fsum, 0, (NF*HD + OUTD + 2)*sizeof(float), stream);

    convert_kernel<<<(WS_U_TOTAL + 320 + 255)/256, 256, 0, stream>>>(
        W1a, b1a, W2a, b2a, W1g, b1g, W2g, b2g, Wih, Whh, wsu, wsf);

    fused_cell_kernel<<<NBLK, 256, 0, stream>>>(
        x, hid, bih, bhh, wsu, wsf, newh, fsum, wsum, sumexp, tsum);

    faction_kernel<<<NCELLS/TBF, 256, 0, stream>>>(newh, fsum, step);

    final_kernel<<<1, 64, 0, stream>>>(Wo, bo, wsum, sumexp, tsum, out);
}

// Round 3
// 307.603 us; speedup vs baseline: 7.5386x; 1.5463x over previous
//
#include <hip/hip_runtime.h>
#include <math.h>

// Problem constants
#define NCELLS 131072
#define IND 64
#define HD 128
#define OUTD 64
#define CATD 192
#define NF 8
#define FS 16384
#define DC 4096
#define TB 64             // cells per fused block
#define NBLK (NCELLS/TB)  // 2048
#define NTH 512

typedef __bf16 bf16x8 __attribute__((ext_vector_type(8)));
typedef float f32x4 __attribute__((ext_vector_type(4)));
typedef unsigned short us8 __attribute__((ext_vector_type(8)));

#define MFMA(a,b,c) __builtin_amdgcn_mfma_f32_16x16x32_bf16(a,b,c,0,0,0)

// ---- workspace layout ----
// ushort (bf16) region:
#define WS_W1F 0          // [256][192]  fused [W1a;W1g]
#define WS_W2F 49152      // [64][256]   fused [W2a | -W2g]
#define WS_WIH 65536      // [384][96]   Wih padded K 65->96 with zeros
#define WS_WHH 102400     // [384][128]
#define WS_U_TOTAL 151552
// float region at (float*)((ushort*)ws + WS_U_TOTAL):
#define WF_B1   0         // [256]
#define WF_B2   256       // [64]
#define WF_FSUM 320       // [8][128]
#define WF_WSUM 1344      // [64]
#define WF_SE   1408
#define WF_TS   1409
#define WF_TOTAL 1412
// aligned newh scratch (fp32, 64MB) at byte offset:
#define WS_NH_OFF 308992  // align256(151552*2 + 1412*4)

// ---- LDS layout (ushort units), total 29696 us = 59392 B ----
// sof/sob/st/se overlay the dead sh1 region after phase 2's reads complete.
#define L_SC   0          // [64][200] us  : c=[x|h] bf16
#define L_SH1  12800      // [64][264] us  : relu(h1) bf16
#define L_SOF  12800      // [64][68] f  (float idx 6400)
#define L_SOB  21504      // [64][104] us : [out|t|0pad] bf16
#define L_ST   28160      // [64] f (float idx 14080)
#define L_SE   28288      // [64] f (float idx 14144)
#define L_TOT  29696

__device__ __forceinline__ unsigned short f2bf(float f) {
    unsigned u = __builtin_bit_cast(unsigned, f);
    return (unsigned short)((u + 0x7FFFu + ((u >> 16) & 1u)) >> 16);
}
__device__ __forceinline__ float bf2f(unsigned short h) {
    return __builtin_bit_cast(float, (unsigned)h << 16);
}
__device__ __forceinline__ bf16x8 ld8(const unsigned short* p) {
    return __builtin_bit_cast(bf16x8, *(const us8*)p);
}
__device__ __forceinline__ float sigm(float v) { return 1.f/(1.f + expf(-v)); }

// ---- per-launch weight conversion fp32 -> bf16 ----
__global__ __launch_bounds__(256) void convert_kernel(
    const float* __restrict__ W1a, const float* __restrict__ b1a,
    const float* __restrict__ W2a, const float* __restrict__ b2a,
    const float* __restrict__ W1g, const float* __restrict__ b1g,
    const float* __restrict__ W2g, const float* __restrict__ b2g,
    const float* __restrict__ Wih, const float* __restrict__ Whh,
    unsigned short* __restrict__ wsu, float* __restrict__ wsf)
{
    int i = blockIdx.x * 256 + threadIdx.x;
    if (i < 49152) {
        int r = i / 192, k = i - r*192;
        float v = (r < 128) ? W1a[r*192 + k] : W1g[(r-128)*192 + k];
        wsu[WS_W1F + i] = f2bf(v); return;
    }
    int j = i - 49152;
    if (j < 16384) {
        int r = j >> 8, k = j & 255;
        float v = (k < 128) ? W2a[r*128 + k] : -W2g[r*128 + (k-128)];
        wsu[WS_W2F + j] = f2bf(v); return;
    }
    j -= 16384;
    if (j < 36864) {
        int r = j / 96, k = j - r*96;
        float v = (k < 65) ? Wih[r*65 + k] : 0.f;
        wsu[WS_WIH + j] = f2bf(v); return;
    }
    j -= 36864;
    if (j < 49152) { wsu[WS_WHH + j] = f2bf(Whh[j]); return; }
    j -= 49152;
    if (j < 256) { wsf[WF_B1 + j] = (j < 128) ? b1a[j] : b1g[j-128]; return; }
    j -= 256;
    if (j < 64)  { wsf[WF_B2 + j] = b2a[j] - b2g[j]; return; }
}

// ---- fused per-cell pipeline, bf16 MFMA, TB=64, 8 waves ----
__global__ __launch_bounds__(NTH, 4) void fused_cell_kernel(
    const float* __restrict__ x, const float* __restrict__ hiddens,
    const float* __restrict__ bih, const float* __restrict__ bhh,
    const unsigned short* __restrict__ wsu, const float* __restrict__ wsf,
    float* __restrict__ newh, float* __restrict__ fsum,
    float* __restrict__ wsum, float* __restrict__ sumexp, float* __restrict__ tsum)
{
    __shared__ __align__(16) unsigned short sm[L_TOT];
    float* smf = (float*)sm;

    const int tid = threadIdx.x;
    const int cell0 = blockIdx.x * TB;
    const int w = tid >> 6, lane = tid & 63;
    const int q = lane >> 4, cL = lane & 15;

    // ---- phase 0: stage c = [x|h] bf16 ----
    for (int idx = tid; idx < TB*IND; idx += NTH) {
        int c = idx >> 6, k = idx & 63;
        sm[L_SC + c*200 + k] = f2bf(x[k]);
    }
    for (int idx = tid; idx < TB*(HD/4); idx += NTH) {
        int c = idx >> 5, k4 = idx & 31;
        float4 v = ((const float4*)hiddens)[(size_t)(cell0+c)*(HD/4) + k4];
        unsigned p0 = (unsigned)f2bf(v.x) | ((unsigned)f2bf(v.y) << 16);
        unsigned p1 = (unsigned)f2bf(v.z) | ((unsigned)f2bf(v.w) << 16);
        *(unsigned*)&sm[L_SC + c*200 + 64 + k4*4]     = p0;
        *(unsigned*)&sm[L_SC + c*200 + 64 + k4*4 + 2] = p1;
    }
    __syncthreads();

    // ---- phase 1: GEMM1  h1 = relu(c @ W1f.T + b1f), cols 256 ----
    // wave w: cols w*32 .. w*32+31 (2 col-tiles), all 4 M-tiles
    #pragma unroll
    for (int ct = 0; ct < 2; ++ct) {
        const int col = w*32 + ct*16 + cL;
        const float bias = wsf[WF_B1 + col];
        f32x4 acc[4];
        #pragma unroll
        for (int m = 0; m < 4; ++m) acc[m] = (f32x4){bias,bias,bias,bias};
        const unsigned short* wp = wsu + WS_W1F + col*192 + q*8;
        #pragma unroll
        for (int k = 0; k < 6; ++k) {
            bf16x8 B = ld8(wp + k*32);
            #pragma unroll
            for (int m = 0; m < 4; ++m) {
                bf16x8 A = ld8(&sm[L_SC + (m*16+cL)*200 + k*32 + q*8]);
                acc[m] = MFMA(A, B, acc[m]);
            }
        }
        #pragma unroll
        for (int m = 0; m < 4; ++m)
            #pragma unroll
            for (int r = 0; r < 4; ++r)
                sm[L_SH1 + (m*16+q*4+r)*264 + col] = f2bf(fmaxf(acc[m][r], 0.f));
    }
    __syncthreads();

    // ---- phase 2: GEMM2  out = h1 @ W2f.T + b2f ----
    // wave w: col-tile (w&3), M-tiles {2*(w>>2), 2*(w>>2)+1}
    f32x4 o0, o1;
    {
        const int col = (w & 3)*16 + cL;
        const int Mt0 = (w >> 2)*2, Mt1 = Mt0 + 1;
        const float bias = wsf[WF_B2 + col];
        o0 = (f32x4){bias,bias,bias,bias}; o1 = o0;
        const unsigned short* wp = wsu + WS_W2F + col*256 + q*8;
        #pragma unroll
        for (int k = 0; k < 8; ++k) {
            bf16x8 B  = ld8(wp + k*32);
            bf16x8 A0 = ld8(&sm[L_SH1 + (Mt0*16+cL)*264 + k*32 + q*8]);
            o0 = MFMA(A0, B, o0);
            bf16x8 A1 = ld8(&sm[L_SH1 + (Mt1*16+cL)*264 + k*32 + q*8]);
            o1 = MFMA(A1, B, o1);
        }
    }
    __syncthreads();   // all sh1 reads done; overlay region now writable

    // ---- phase 2b: write out tiles into overlay (sof fp32, sob bf16); zero pads ----
    {
        const int col = (w & 3)*16 + cL;
        const int Mt0 = (w >> 2)*2, Mt1 = Mt0 + 1;
        #pragma unroll
        for (int r = 0; r < 4; ++r) {
            int r0 = Mt0*16 + q*4 + r, r1 = Mt1*16 + q*4 + r;
            smf[L_SOF/2 + r0*68 + col] = o0[r];
            sm [L_SOB   + r0*104 + col] = f2bf(o0[r]);
            smf[L_SOF/2 + r1*68 + col] = o1[r];
            sm [L_SOB   + r1*104 + col] = f2bf(o1[r]);
        }
    }
    for (int idx = tid; idx < TB*32; idx += NTH) {   // sob cols 64..95 = 0
        int c = idx >> 5, k = idx & 31;
        sm[L_SOB + c*104 + 64 + k] = 0;
    }
    __syncthreads();

    // ---- phase 3: t = mean(out^2), e^t, t into sob col 64 ----
    if (tid < TB) {
        float s = 0.f;
        #pragma unroll 8
        for (int jj = 0; jj < OUTD; ++jj) { float v = smf[L_SOF/2 + tid*68 + jj]; s += v*v; }
        float t = s * (1.0f/OUTD);
        smf[L_ST/2 + tid] = t; smf[L_SE/2 + tid] = expf(t);
        sm[L_SOB + tid*104 + 64] = f2bf(t);
    }
    __syncthreads();

    // ---- phase 4: GRU gates (MFMA, B-frags reused across 2 M-tiles) ----
    const int f = (int)(blockIdx.x >> 8);     // 256 blocks per faction
    {
        const int j = w*16 + cL;              // hidden unit for this lane
        const float bR = bih[j]        + bhh[j];
        const float bZ = bih[HD+j]     + bhh[HD+j];
        const float bI = bih[2*HD+j];
        const float bH = bhh[2*HD+j];
        float colsum = 0.f;
        #pragma unroll
        for (int half = 0; half < 2; ++half) {
            const int Mt0 = half*2, Mt1 = Mt0 + 1;
            f32x4 R0 = {bR,bR,bR,bR}, R1 = R0;
            f32x4 Z0 = {bZ,bZ,bZ,bZ}, Z1 = Z0;
            f32x4 I0 = {bI,bI,bI,bI}, I1 = I0;
            f32x4 H0 = {bH,bH,bH,bH}, H1 = H0;
            const unsigned short* wi = wsu + WS_WIH + q*8;
            #pragma unroll
            for (int k = 0; k < 3; ++k) {     // gi: K=96
                bf16x8 Br = ld8(wi + (size_t)j*96        + k*32);
                bf16x8 Bz = ld8(wi + (size_t)(HD+j)*96   + k*32);
                bf16x8 Bi = ld8(wi + (size_t)(2*HD+j)*96 + k*32);
                bf16x8 A0 = ld8(&sm[L_SOB + (Mt0*16+cL)*104 + k*32 + q*8]);
                bf16x8 A1 = ld8(&sm[L_SOB + (Mt1*16+cL)*104 + k*32 + q*8]);
                R0 = MFMA(A0, Br, R0); R1 = MFMA(A1, Br, R1);
                Z0 = MFMA(A0, Bz, Z0); Z1 = MFMA(A1, Bz, Z1);
                I0 = MFMA(A0, Bi, I0); I1 = MFMA(A1, Bi, I1);
            }
            const unsigned short* wh = wsu + WS_WHH + q*8;
            #pragma unroll
            for (int k = 0; k < 4; ++k) {     // gh: K=128
                bf16x8 Br = ld8(wh + (size_t)j*128        + k*32);
                bf16x8 Bz = ld8(wh + (size_t)(HD+j)*128   + k*32);
                bf16x8 Bn = ld8(wh + (size_t)(2*HD+j)*128 + k*32);
                bf16x8 A0 = ld8(&sm[L_SC + (Mt0*16+cL)*200 + 64 + k*32 + q*8]);
                bf16x8 A1 = ld8(&sm[L_SC + (Mt1*16+cL)*200 + 64 + k*32 + q*8]);
                R0 = MFMA(A0, Br, R0); R1 = MFMA(A1, Br, R1);
                Z0 = MFMA(A0, Bz, Z0); Z1 = MFMA(A1, Bz, Z1);
                H0 = MFMA(A0, Bn, H0); H1 = MFMA(A1, Bn, H1);
            }
            #pragma unroll
            for (int r = 0; r < 4; ++r) {
                int row = Mt0*16 + q*4 + r;
                float rr = sigm(R0[r]), zz = sigm(Z0[r]);
                float nn = tanhf(I0[r] + rr*H0[r]);
                float hold = bf2f(sm[L_SC + row*200 + 64 + j]);
                float hv = (1.f - zz)*nn + zz*hold;
                newh[(size_t)(cell0+row)*HD + j] = hv;
                colsum += hv;
            }
            #pragma unroll
            for (int r = 0; r < 4; ++r) {
                int row = Mt1*16 + q*4 + r;
                float rr = sigm(R1[r]), zz = sigm(Z1[r]);
                float nn = tanhf(I1[r] + rr*H1[r]);
                float hold = bf2f(sm[L_SC + row*200 + 64 + j]);
                float hv = (1.f - zz)*nn + zz*hold;
                newh[(size_t)(cell0+row)*HD + j] = hv;
                colsum += hv;
            }
        }
        colsum += __shfl_xor(colsum, 16);
        colsum += __shfl_xor(colsum, 32);
        if (q == 0) unsafeAtomicAdd(&fsum[f*HD + j], colsum);
    }

    // ---- phase 5: softmax-weighted sums (reads only pre-ph4 LDS) ----
    if (tid < OUTD) {
        float wacc = 0.f;
        #pragma unroll 4
        for (int c = 0; c < TB; ++c) wacc += smf[L_SE/2 + c] * smf[L_SOF/2 + c*68 + tid];
        unsafeAtomicAdd(&wsum[tid], wacc);
    }
    if (tid == 0) {
        float sE = 0.f, sT = 0.f;
        #pragma unroll 4
        for (int c = 0; c < TB; ++c) { sE += smf[L_SE/2 + c]; sT += smf[L_ST/2 + c]; }
        unsafeAtomicAdd(sumexp, sE);
        unsafeAtomicAdd(tsum, sT);
    }
}

// ---- faction sync: dst = a*src + b[j], block-uniform debate ----
#define TBF 64
__global__ __launch_bounds__(256) void faction_kernel(
    const float* __restrict__ src, float* __restrict__ dst,
    const float* __restrict__ fsum, const int* __restrict__ step)
{
    __shared__ float bnon[HD], bdeb[HD];
    const int cell0 = blockIdx.x * TBF;
    const int f = blockIdx.x >> 8;            // 256 blocks per faction
    if (threadIdx.x < HD) {
        const int j = threadIdx.x;
        float s = 0.f;
        #pragma unroll
        for (int ff = 0; ff < NF; ++ff) s += fsum[ff*HD + j];
        const float go = s * (1.0f/NCELLS);
        const float fm = fsum[f*HD + j] * (1.0f/FS);
        bnon[j] = 0.15f*fm;
        bdeb[j] = 0.1275f*fm + 0.15f*go;
    }
    __syncthreads();
    const bool debate = (step[0] > 5) && ((cell0 & (FS-1)) < DC);  // uniform per block
    const float a = debate ? 0.7225f : 0.85f;
    const float* brow = debate ? bdeb : bnon;
    #pragma unroll
    for (int i = 0; i < (TBF*HD)/256; ++i) {
        const int idx = threadIdx.x + i*256;
        const int j = idx & 127;
        const size_t e = (size_t)cell0*HD + idx;
        dst[e] = a*src[e] + brow[j];
    }
}

__global__ void final_kernel(const float* __restrict__ Wo, const float* __restrict__ bo,
                             const float* __restrict__ wsum, const float* __restrict__ sumexp,
                             const float* __restrict__ tsum, float* __restrict__ d_out)
{
    const int i = threadIdx.x;
    if (i < OUTD) {
        const float inv = 1.0f / sumexp[0];
        const float* wr = Wo + (size_t)i*OUTD;
        float acc = bo[i];
        for (int jj = 0; jj < OUTD; ++jj) acc += (wsum[jj]*inv) * wr[jj];
        d_out[i] = acc;
    }
    if (i == 0) d_out[OUTD] = tsum[0] * (1.0f/NCELLS);
}

extern "C" void kernel_launch(void* const* d_in, const int* in_sizes, int n_in,
                              void* d_out, int out_size, void* d_ws, size_t ws_size,
                              hipStream_t stream)
{
    const float* x   = (const float*)d_in[0];
    const float* hid = (const float*)d_in[1];
    const float* W1a = (const float*)d_in[2];
    const float* b1a = (const float*)d_in[3];
    const float* W2a = (const float*)d_in[4];
    const float* b2a = (const float*)d_in[5];
    const float* W1g = (const float*)d_in[6];
    const float* b1g = (const float*)d_in[7];
    const float* W2g = (const float*)d_in[8];
    const float* b2g = (const float*)d_in[9];
    const float* Wih = (const float*)d_in[10];
    const float* Whh = (const float*)d_in[11];
    const float* bih = (const float*)d_in[12];
    const float* bhh = (const float*)d_in[13];
    const float* Wo  = (const float*)d_in[14];
    const float* bo  = (const float*)d_in[15];
    const int*  step = (const int*)d_in[16];

    float* out  = (float*)d_out;
    float* newh_out = out + (OUTD + 1);

    unsigned short* wsu = (unsigned short*)d_ws;
    float* wsf = (float*)(wsu + WS_U_TOTAL);
    float* fsum   = wsf + WF_FSUM;
    float* wsum   = wsf + WF_WSUM;
    float* sumexp = wsf + WF_SE;
    float* tsum   = wsf + WF_TS;

    // aligned pre-sync newh scratch if workspace allows; else in-place in d_out
    const size_t need = (size_t)WS_NH_OFF + (size_t)NCELLS*HD*sizeof(float);
    float* nh_store = (ws_size >= need) ? (float*)((char*)d_ws + WS_NH_OFF) : newh_out;

    hipMemsetAsync(fsum, 0, (NF*HD + OUTD + 2)*sizeof(float), stream);

    convert_kernel<<<(151872 + 255)/256, 256, 0, stream>>>(
        W1a, b1a, W2a, b2a, W1g, b1g, W2g, b2g, Wih, Whh, wsu, wsf);

    fused_cell_kernel<<<NBLK, NTH, 0, stream>>>(
        x, hid, bih, bhh, wsu, wsf, nh_store, fsum, wsum, sumexp, tsum);

    faction_kernel<<<NCELLS/TBF, 256, 0, stream>>>(nh_store, newh_out, fsum, step);

    final_kernel<<<1, 64, 0, stream>>>(Wo, bo, wsum, sumexp, tsum, out);
}